// Round 6
// baseline (130.449 us; speedup 1.0000x reference)
//
#include <hip/hip_runtime.h>
#include <hip/hip_bf16.h>
#include <math.h>

// Problem constants
#define QN 2048
#define CN 10
#define SN 16
#define DN 256
#define H1N 256
#define H2N 128
#define H3N 64
#define H4N 10
#define NROW 160        // C*S support rows
#define PRE_AB_BLOCKS (QN / 4 + NROW / 4)   // 552

typedef __attribute__((ext_vector_type(8)))  short  bf16x8s;  // 8 bf16 = 4 VGPR
typedef __attribute__((ext_vector_type(4)))  float  f32x4;
typedef __attribute__((ext_vector_type(16))) float  f32x16;

static __device__ __forceinline__ unsigned short f2bf(float f) {
  // scalar cast -> compiler fuses pairs into v_cvt_pk_bf16_f32 (RNE)
  __hip_bfloat16 h = __float2bfloat16(f);
  return __builtin_bit_cast(unsigned short, h);
}

static __device__ __forceinline__ float fast_tanh(float x) {
  const float xc = fminf(fmaxf(x, -15.f), 15.f);
  const float e = __expf(2.f * xc);
  return (e - 1.f) / (e + 1.f);
}

// ---------------------------------------------------------------------------
// Kernel 1 (merged): layer-1 factorization + weight fragment packing.
//  blocks [0, 552):   A[q][j] = b1[j] + q . W1[:,j] ; Bm[i][j] = s . W1[256+,:j]
//  blocks [552, 573): pack W2/W3/W4 -> fb2/fb3/fb4 fragment-linear bf16
//    (4 frags per block: f = (bid-552)*4 + (t>>6), lane = t&63)
// ---------------------------------------------------------------------------
__global__ __launch_bounds__(256) void k_pre(
    const float* __restrict__ queries, const float* __restrict__ supports,
    const float* __restrict__ W1, const float* __restrict__ b1,
    const float* __restrict__ W2, const float* __restrict__ W3,
    const float* __restrict__ W4,
    float* __restrict__ A, float* __restrict__ Bm,
    ushort* __restrict__ fb2, ushort* __restrict__ fb3, ushort* __restrict__ fb4) {
  __shared__ float xs[4][DN];
  const int bid = blockIdx.x;
  const int t = threadIdx.x;

  if (bid < PRE_AB_BLOCKS) {
    const bool isA = bid < (QN / 4);
    const int row0 = isA ? bid * 4 : (bid - QN / 4) * 4;
    const float* src = isA ? (queries + (size_t)row0 * DN) : (supports + (size_t)row0 * DN);
    for (int r = 0; r < 4; ++r) xs[r][t] = src[r * DN + t];
    __syncthreads();
    const float* w = W1 + (isA ? 0 : DN * H1N) + t;  // column t
    float acc0 = 0.f, acc1 = 0.f, acc2 = 0.f, acc3 = 0.f;
#pragma unroll 8
    for (int d = 0; d < DN; ++d) {
      const float wv = w[(size_t)d * H1N];
      acc0 += xs[0][d] * wv;
      acc1 += xs[1][d] * wv;
      acc2 += xs[2][d] * wv;
      acc3 += xs[3][d] * wv;
    }
    const float bias = isA ? b1[t] : 0.f;
    float* dst = isA ? A : Bm;
    dst[(row0 + 0) * H1N + t] = acc0 + bias;
    dst[(row0 + 1) * H1N + t] = acc1 + bias;
    dst[(row0 + 2) * H1N + t] = acc2 + bias;
    dst[(row0 + 3) * H1N + t] = acc3 + bias;
    return;
  }

  // ---- weight packing ----
  const int f = (bid - PRE_AB_BLOCKS) * 4 + (t >> 6);
  const int l = t & 63;
  if (f >= 82) return;
  ushort o[8];
  if (f < 64) {
    const int ct = f >> 4, ks = f & 15;
    const int col = ct * 32 + (l & 31);
    const int k0 = ks * 16 + (l >> 5) * 8;
#pragma unroll
    for (int j = 0; j < 8; ++j) o[j] = f2bf(W2[(size_t)(k0 + j) * H2N + col]);
#pragma unroll
    for (int j = 0; j < 8; ++j) fb2[(size_t)f * 512 + l * 8 + j] = o[j];
  } else if (f < 80) {
    const int g = f - 64;
    const int ct = g >> 3, ks = g & 7;
    const int col = ct * 32 + (l & 31);
    const int k0 = ks * 16 + (l >> 5) * 8;
#pragma unroll
    for (int j = 0; j < 8; ++j) o[j] = f2bf(W3[(size_t)(k0 + j) * H3N + col]);
#pragma unroll
    for (int j = 0; j < 8; ++j) fb3[(size_t)g * 512 + l * 8 + j] = o[j];
  } else {
    const int ks = f - 80;
    const int col = l & 15;
    const int k0 = ks * 32 + (l >> 4) * 8;
#pragma unroll
    for (int j = 0; j < 8; ++j)
      o[j] = (col < H4N) ? f2bf(W4[(size_t)(k0 + j) * H4N + col]) : (ushort)0;
#pragma unroll
    for (int j = 0; j < 8; ++j) fb4[(size_t)ks * 512 + l * 8 + j] = o[j];
  }
}

// ---------------------------------------------------------------------------
// Kernel 2: MFMA layers 2-4 + tanh + mean + item-sum.
// Block = 64 rows, 4 waves in 2x2 (wr = row-half, wc = col-half).
// LDS 32 KB: h2s/h3s ALIAS the h1s region (h1 dead after GEMM2 reads; the
// extra barrier between GEMM2's MFMA loop and the h2s writes makes it safe).
// -> 4-5 blocks/CU instead of 2 (latency hiding was the round-5 bottleneck).
// ---------------------------------------------------------------------------
__global__ __launch_bounds__(256, 4) void k_main(
    const float* __restrict__ A, const float* __restrict__ Bm,
    const ushort* __restrict__ fb2, const ushort* __restrict__ fb3,
    const ushort* __restrict__ fb4,
    const float* __restrict__ b2, const float* __restrict__ b3,
    const float* __restrict__ b4, float* __restrict__ out) {
  __shared__ __align__(16) unsigned char smem[64 * 512];   // 32 KB
  unsigned char* h1s = smem;                 // [64][256 bf16] swizzled
  unsigned char* h2s = smem;                 // [64][128 bf16] (aliases h1s)
  unsigned char* h3s = smem + 64 * 256;      // [64][64 bf16]  (disjoint from h2s)

  const int t = threadIdx.x;
  const int wid = t >> 6;
  const int l = t & 63;
  const int l31 = l & 31;
  const int l15 = l & 15;
  const int sw = (l & 7) << 4;
  const int wr = wid >> 1, wc = wid & 1;

  // ---- B2 fragments: 2 col-tiles x 16 k-steps, coalesced global loads
  bf16x8s B2[2][16];
  const bf16x8s* fb2v = (const bf16x8s*)fb2;
#pragma unroll
  for (int ct = 0; ct < 2; ++ct) {
    const int ctg = wc * 2 + ct;
#pragma unroll
    for (int ks = 0; ks < 16; ++ks) B2[ct][ks] = fb2v[(ctg * 16 + ks) * 64 + l];
  }

  // ---- stage h1 = relu(A[q] + Bm[b]) -> LDS bf16
  const int rg0 = blockIdx.x * 64;
  const int q0 = rg0 / NROW;
  const int b0 = rg0 - q0 * NROW;
#pragma unroll 4
  for (int r = 0; r < 16; ++r) {
    const int row = wid * 16 + r;           // wave-uniform
    int bb = b0 + row;
    int qq = q0;
    if (bb >= NROW) { bb -= NROW; qq += 1; }
    const float4 av = *(const float4*)(A + (size_t)qq * DN + l * 4);
    const float4 bv = *(const float4*)(Bm + (size_t)bb * DN + l * 4);
    ushort4 o;
    o.x = f2bf(fmaxf(av.x + bv.x, 0.f));
    o.y = f2bf(fmaxf(av.y + bv.y, 0.f));
    o.z = f2bf(fmaxf(av.z + bv.z, 0.f));
    o.w = f2bf(fmaxf(av.w + bv.w, 0.f));
    *(ushort4*)(h1s + row * 512 + ((l * 8) ^ ((row & 7) << 4))) = o;
  }
  __syncthreads();

  // ---- GEMM2: h2 = relu(h1 @ W2 + b2)
  f32x16 acc2a, acc2b;
#pragma unroll
  for (int i = 0; i < 16; ++i) { acc2a[i] = 0.f; acc2b[i] = 0.f; }
  {
    const unsigned char* abase = h1s + (32 * wr + l31) * 512;
    const int kh = (l >> 5) * 16;
#pragma unroll
    for (int ks = 0; ks < 16; ++ks) {
      const bf16x8s a = *(const bf16x8s*)(abase + ((ks * 32 + kh) ^ sw));
      acc2a = __builtin_amdgcn_mfma_f32_32x32x16_bf16(a, B2[0][ks], acc2a, 0, 0, 0);
      acc2b = __builtin_amdgcn_mfma_f32_32x32x16_bf16(a, B2[1][ks], acc2b, 0, 0, 0);
    }
  }
  __syncthreads();   // all h1s reads complete before h2s (alias) writes
  {
    const int c0 = 64 * wc + l31;
    const float bias0 = b2[c0], bias1 = b2[c0 + 32];
    const int cb0 = c0 * 2;
#pragma unroll
    for (int reg = 0; reg < 16; ++reg) {
      const int row = 32 * wr + (reg & 3) + 8 * (reg >> 2) + 4 * (l >> 5);
      const int rsw = (row & 7) << 4;
      *(ushort*)(h2s + row * 256 + (cb0 ^ rsw)) =
          f2bf(fmaxf(acc2a[reg] + bias0, 0.f));
      *(ushort*)(h2s + row * 256 + ((cb0 + 64) ^ rsw)) =
          f2bf(fmaxf(acc2b[reg] + bias1, 0.f));
    }
  }
  __syncthreads();

  // ---- GEMM3: h3 = relu(h2 @ W3 + b3)
  bf16x8s B3[8];
  const bf16x8s* fb3v = (const bf16x8s*)fb3;
#pragma unroll
  for (int ks = 0; ks < 8; ++ks) B3[ks] = fb3v[(wc * 8 + ks) * 64 + l];
  f32x16 acc3;
#pragma unroll
  for (int i = 0; i < 16; ++i) acc3[i] = 0.f;
  {
    const unsigned char* abase = h2s + (32 * wr + l31) * 256;
    const int kh = (l >> 5) * 16;
#pragma unroll
    for (int ks = 0; ks < 8; ++ks) {
      const bf16x8s a = *(const bf16x8s*)(abase + ((ks * 32 + kh) ^ sw));
      acc3 = __builtin_amdgcn_mfma_f32_32x32x16_bf16(a, B3[ks], acc3, 0, 0, 0);
    }
  }
  // h3s writes are to a region disjoint from h2s reads -> no barrier needed
  {
    const int c = 32 * wc + l31;
    const float bias = b3[c];
#pragma unroll
    for (int reg = 0; reg < 16; ++reg) {
      const int row = 32 * wr + (reg & 3) + 8 * (reg >> 2) + 4 * (l >> 5);
      const int rsw = (row & 7) << 4;
      *(ushort*)(h3s + row * 128 + ((c * 2) ^ rsw)) =
          f2bf(fmaxf(acc3[reg] + bias, 0.f));
    }
  }
  __syncthreads();

  // ---- GEMM4 (16x16x32): wave wid owns rows 16*wid..+16 (one (q,c) group)
  bf16x8s B4[2];
  const bf16x8s* fb4v = (const bf16x8s*)fb4;
  B4[0] = fb4v[l];
  B4[1] = fb4v[64 + l];
  f32x4 acc4;
#pragma unroll
  for (int i = 0; i < 4; ++i) acc4[i] = 0.f;
  {
    const unsigned char* abase = h3s + (16 * wid + l15) * 128;
#pragma unroll
    for (int ks = 0; ks < 2; ++ks) {
      const bf16x8s a =
          *(const bf16x8s*)(abase + ((((l >> 4) * 16) + ks * 64) ^ sw));
      acc4 = __builtin_amdgcn_mfma_f32_16x16x32_bf16(a, B4[ks], acc4, 0, 0, 0);
    }
  }

  // ---- epilogue: tanh, sum 10 cols, mean, sum 16 rows -> score
  {
    const int col = l15;
    const float b4v = (col < H4N) ? b4[col] : 0.f;
    float part = 0.f;
#pragma unroll
    for (int r = 0; r < 4; ++r) {
      const float v = fast_tanh(acc4[r] + b4v);
      part += (col < H4N) ? v : 0.f;
    }
    part += __shfl_xor(part, 1);
    part += __shfl_xor(part, 2);
    part += __shfl_xor(part, 4);
    part += __shfl_xor(part, 8);
    part += __shfl_xor(part, 16);
    part += __shfl_xor(part, 32);
    if (l == 0) out[(size_t)blockIdx.x * 4 + wid] = part * 0.1f;
  }
}

// ---------------------------------------------------------------------------
extern "C" void kernel_launch(void* const* d_in, const int* in_sizes, int n_in,
                              void* d_out, int out_size, void* d_ws, size_t ws_size,
                              hipStream_t stream) {
  const float* queries  = (const float*)d_in[0];
  const float* supports = (const float*)d_in[1];
  const float* W1 = (const float*)d_in[2];
  const float* b1 = (const float*)d_in[3];
  const float* W2 = (const float*)d_in[4];
  const float* b2 = (const float*)d_in[5];
  const float* W3 = (const float*)d_in[6];
  const float* b3 = (const float*)d_in[7];
  const float* W4 = (const float*)d_in[8];
  const float* b4 = (const float*)d_in[9];
  float* out = (float*)d_out;

  // workspace layout (fp32 A/Bm, then bf16 fragment buffers) ~2.35 MB
  float* A  = (float*)d_ws;                       // [2048][256]
  float* Bm = A + (size_t)QN * H1N;               // [160][256]
  ushort* fb2 = (ushort*)(Bm + (size_t)NROW * H1N);  // 64*512
  ushort* fb3 = fb2 + 64 * 512;                      // 16*512
  ushort* fb4 = fb3 + 16 * 512;                      // 2*512

  hipLaunchKernelGGL(k_pre, dim3(PRE_AB_BLOCKS + 21), dim3(256), 0, stream,
                     queries, supports, W1, b1, W2, W3, W4, A, Bm, fb2, fb3, fb4);
  hipLaunchKernelGGL(k_main, dim3((QN * CN * SN) / 64), dim3(256), 0, stream,
                     A, Bm, fb2, fb3, fb4, b2, b3, b4, out);
}

// Round 7
// 82.270 us; speedup vs baseline: 1.5856x; 1.5856x over previous
//
#include <hip/hip_runtime.h>
#include <hip/hip_bf16.h>
#include <math.h>

// Problem constants
#define QN 2048
#define CN 10
#define SN 16
#define DN 256
#define H1N 256
#define H2N 128
#define H3N 64
#define H4N 10
#define NROW 160        // C*S support rows
#define PRE_AB_BLOCKS (QN / 4 + NROW / 4)   // 552

typedef __attribute__((ext_vector_type(8)))  short  bf16x8s;  // 8 bf16 = 4 VGPR
typedef __attribute__((ext_vector_type(4)))  float  f32x4;
typedef __attribute__((ext_vector_type(16))) float  f32x16;

static __device__ __forceinline__ unsigned short f2bf(float f) {
  // scalar cast -> compiler fuses pairs into v_cvt_pk_bf16_f32 (RNE)
  __hip_bfloat16 h = __float2bfloat16(f);
  return __builtin_bit_cast(unsigned short, h);
}

static __device__ __forceinline__ float fast_tanh(float x) {
  const float xc = fminf(fmaxf(x, -15.f), 15.f);
  const float e = __expf(2.f * xc);
  return (e - 1.f) / (e + 1.f);
}

// ---------------------------------------------------------------------------
// Kernel 1 (merged): layer-1 factorization + weight fragment packing.
//  blocks [0, 552):   A[q][j] = b1[j] + q . W1[:,j] ; Bm[i][j] = s . W1[256+,:j]
//  blocks [552, 573): pack W2/W3/W4 -> fb2/fb3/fb4 fragment-linear bf16
// ---------------------------------------------------------------------------
__global__ __launch_bounds__(256) void k_pre(
    const float* __restrict__ queries, const float* __restrict__ supports,
    const float* __restrict__ W1, const float* __restrict__ b1,
    const float* __restrict__ W2, const float* __restrict__ W3,
    const float* __restrict__ W4,
    float* __restrict__ A, float* __restrict__ Bm,
    ushort* __restrict__ fb2, ushort* __restrict__ fb3, ushort* __restrict__ fb4) {
  __shared__ float xs[4][DN];
  const int bid = blockIdx.x;
  const int t = threadIdx.x;

  if (bid < PRE_AB_BLOCKS) {
    const bool isA = bid < (QN / 4);
    const int row0 = isA ? bid * 4 : (bid - QN / 4) * 4;
    const float* src = isA ? (queries + (size_t)row0 * DN) : (supports + (size_t)row0 * DN);
    for (int r = 0; r < 4; ++r) xs[r][t] = src[r * DN + t];
    __syncthreads();
    const float* w = W1 + (isA ? 0 : DN * H1N) + t;  // column t
    float acc0 = 0.f, acc1 = 0.f, acc2 = 0.f, acc3 = 0.f;
#pragma unroll 8
    for (int d = 0; d < DN; ++d) {
      const float wv = w[(size_t)d * H1N];
      acc0 += xs[0][d] * wv;
      acc1 += xs[1][d] * wv;
      acc2 += xs[2][d] * wv;
      acc3 += xs[3][d] * wv;
    }
    const float bias = isA ? b1[t] : 0.f;
    float* dst = isA ? A : Bm;
    dst[(row0 + 0) * H1N + t] = acc0 + bias;
    dst[(row0 + 1) * H1N + t] = acc1 + bias;
    dst[(row0 + 2) * H1N + t] = acc2 + bias;
    dst[(row0 + 3) * H1N + t] = acc3 + bias;
    return;
  }

  // ---- weight packing ----
  const int f = (bid - PRE_AB_BLOCKS) * 4 + (t >> 6);
  const int l = t & 63;
  if (f >= 82) return;
  ushort o[8];
  if (f < 64) {
    const int ct = f >> 4, ks = f & 15;
    const int col = ct * 32 + (l & 31);
    const int k0 = ks * 16 + (l >> 5) * 8;
#pragma unroll
    for (int j = 0; j < 8; ++j) o[j] = f2bf(W2[(size_t)(k0 + j) * H2N + col]);
#pragma unroll
    for (int j = 0; j < 8; ++j) fb2[(size_t)f * 512 + l * 8 + j] = o[j];
  } else if (f < 80) {
    const int g = f - 64;
    const int ct = g >> 3, ks = g & 7;
    const int col = ct * 32 + (l & 31);
    const int k0 = ks * 16 + (l >> 5) * 8;
#pragma unroll
    for (int j = 0; j < 8; ++j) o[j] = f2bf(W3[(size_t)(k0 + j) * H3N + col]);
#pragma unroll
    for (int j = 0; j < 8; ++j) fb3[(size_t)g * 512 + l * 8 + j] = o[j];
  } else {
    const int ks = f - 80;
    const int col = l & 15;
    const int k0 = ks * 32 + (l >> 4) * 8;
#pragma unroll
    for (int j = 0; j < 8; ++j)
      o[j] = (col < H4N) ? f2bf(W4[(size_t)(k0 + j) * H4N + col]) : (ushort)0;
#pragma unroll
    for (int j = 0; j < 8; ++j) fb4[(size_t)ks * 512 + l * 8 + j] = o[j];
  }
}

// ---------------------------------------------------------------------------
// Kernel 2: MFMA layers 2-4 + tanh + mean + item-sum.
// Block = 64 rows, 4 waves in 2x2 (wr = row-half, wc = col-half).
// LDS 32 KB: h2s/h3s ALIAS the h1s region (extra barrier makes it safe).
// __launch_bounds__(256, 3): VGPR cap ~170 — round 6's (256,4) cap of 128
// spilled B2[2][16]+accs to scratch (WRITE_SIZE 160KB -> 225MB, 1.5x slower).
// ---------------------------------------------------------------------------
__global__ __launch_bounds__(256, 3) void k_main(
    const float* __restrict__ A, const float* __restrict__ Bm,
    const ushort* __restrict__ fb2, const ushort* __restrict__ fb3,
    const ushort* __restrict__ fb4,
    const float* __restrict__ b2, const float* __restrict__ b3,
    const float* __restrict__ b4, float* __restrict__ out) {
  __shared__ __align__(16) unsigned char smem[64 * 512];   // 32 KB
  unsigned char* h1s = smem;                 // [64][256 bf16] swizzled
  unsigned char* h2s = smem;                 // [64][128 bf16] (aliases h1s)
  unsigned char* h3s = smem + 64 * 256;      // [64][64 bf16]  (disjoint from h2s)

  const int t = threadIdx.x;
  const int wid = t >> 6;
  const int l = t & 63;
  const int l31 = l & 31;
  const int l15 = l & 15;
  const int sw = (l & 7) << 4;
  const int wr = wid >> 1, wc = wid & 1;

  // ---- B2 fragments: 2 col-tiles x 16 k-steps, coalesced global loads
  bf16x8s B2[2][16];
  const bf16x8s* fb2v = (const bf16x8s*)fb2;
#pragma unroll
  for (int ct = 0; ct < 2; ++ct) {
    const int ctg = wc * 2 + ct;
#pragma unroll
    for (int ks = 0; ks < 16; ++ks) B2[ct][ks] = fb2v[(ctg * 16 + ks) * 64 + l];
  }

  // ---- stage h1 = relu(A[q] + Bm[b]) -> LDS bf16
  const int rg0 = blockIdx.x * 64;
  const int q0 = rg0 / NROW;
  const int b0 = rg0 - q0 * NROW;
#pragma unroll 4
  for (int r = 0; r < 16; ++r) {
    const int row = wid * 16 + r;           // wave-uniform
    int bb = b0 + row;
    int qq = q0;
    if (bb >= NROW) { bb -= NROW; qq += 1; }
    const float4 av = *(const float4*)(A + (size_t)qq * DN + l * 4);
    const float4 bv = *(const float4*)(Bm + (size_t)bb * DN + l * 4);
    ushort4 o;
    o.x = f2bf(fmaxf(av.x + bv.x, 0.f));
    o.y = f2bf(fmaxf(av.y + bv.y, 0.f));
    o.z = f2bf(fmaxf(av.z + bv.z, 0.f));
    o.w = f2bf(fmaxf(av.w + bv.w, 0.f));
    *(ushort4*)(h1s + row * 512 + ((l * 8) ^ ((row & 7) << 4))) = o;
  }
  __syncthreads();

  // ---- GEMM2: h2 = relu(h1 @ W2 + b2)
  f32x16 acc2a, acc2b;
#pragma unroll
  for (int i = 0; i < 16; ++i) { acc2a[i] = 0.f; acc2b[i] = 0.f; }
  {
    const unsigned char* abase = h1s + (32 * wr + l31) * 512;
    const int kh = (l >> 5) * 16;
#pragma unroll
    for (int ks = 0; ks < 16; ++ks) {
      const bf16x8s a = *(const bf16x8s*)(abase + ((ks * 32 + kh) ^ sw));
      acc2a = __builtin_amdgcn_mfma_f32_32x32x16_bf16(a, B2[0][ks], acc2a, 0, 0, 0);
      acc2b = __builtin_amdgcn_mfma_f32_32x32x16_bf16(a, B2[1][ks], acc2b, 0, 0, 0);
    }
  }
  __syncthreads();   // all h1s reads complete before h2s (alias) writes
  {
    const int c0 = 64 * wc + l31;
    const float bias0 = b2[c0], bias1 = b2[c0 + 32];
    const int cb0 = c0 * 2;
#pragma unroll
    for (int reg = 0; reg < 16; ++reg) {
      const int row = 32 * wr + (reg & 3) + 8 * (reg >> 2) + 4 * (l >> 5);
      const int rsw = (row & 7) << 4;
      *(ushort*)(h2s + row * 256 + (cb0 ^ rsw)) =
          f2bf(fmaxf(acc2a[reg] + bias0, 0.f));
      *(ushort*)(h2s + row * 256 + ((cb0 + 64) ^ rsw)) =
          f2bf(fmaxf(acc2b[reg] + bias1, 0.f));
    }
  }
  __syncthreads();

  // ---- GEMM3: h3 = relu(h2 @ W3 + b3)
  bf16x8s B3[8];
  const bf16x8s* fb3v = (const bf16x8s*)fb3;
#pragma unroll
  for (int ks = 0; ks < 8; ++ks) B3[ks] = fb3v[(wc * 8 + ks) * 64 + l];
  f32x16 acc3;
#pragma unroll
  for (int i = 0; i < 16; ++i) acc3[i] = 0.f;
  {
    const unsigned char* abase = h2s + (32 * wr + l31) * 256;
    const int kh = (l >> 5) * 16;
#pragma unroll
    for (int ks = 0; ks < 8; ++ks) {
      const bf16x8s a = *(const bf16x8s*)(abase + ((ks * 32 + kh) ^ sw));
      acc3 = __builtin_amdgcn_mfma_f32_32x32x16_bf16(a, B3[ks], acc3, 0, 0, 0);
    }
  }
  // h3s writes are to a region disjoint from h2s reads -> no barrier needed
  {
    const int c = 32 * wc + l31;
    const float bias = b3[c];
#pragma unroll
    for (int reg = 0; reg < 16; ++reg) {
      const int row = 32 * wr + (reg & 3) + 8 * (reg >> 2) + 4 * (l >> 5);
      const int rsw = (row & 7) << 4;
      *(ushort*)(h3s + row * 128 + ((c * 2) ^ rsw)) =
          f2bf(fmaxf(acc3[reg] + bias, 0.f));
    }
  }
  __syncthreads();

  // ---- GEMM4 (16x16x32): wave wid owns rows 16*wid..+16 (one (q,c) group)
  bf16x8s B4[2];
  const bf16x8s* fb4v = (const bf16x8s*)fb4;
  B4[0] = fb4v[l];
  B4[1] = fb4v[64 + l];
  f32x4 acc4;
#pragma unroll
  for (int i = 0; i < 4; ++i) acc4[i] = 0.f;
  {
    const unsigned char* abase = h3s + (16 * wid + l15) * 128;
#pragma unroll
    for (int ks = 0; ks < 2; ++ks) {
      const bf16x8s a =
          *(const bf16x8s*)(abase + ((((l >> 4) * 16) + ks * 64) ^ sw));
      acc4 = __builtin_amdgcn_mfma_f32_16x16x32_bf16(a, B4[ks], acc4, 0, 0, 0);
    }
  }

  // ---- epilogue: tanh, sum 10 cols, mean, sum 16 rows -> score
  {
    const int col = l15;
    const float b4v = (col < H4N) ? b4[col] : 0.f;
    float part = 0.f;
#pragma unroll
    for (int r = 0; r < 4; ++r) {
      const float v = fast_tanh(acc4[r] + b4v);
      part += (col < H4N) ? v : 0.f;
    }
    part += __shfl_xor(part, 1);
    part += __shfl_xor(part, 2);
    part += __shfl_xor(part, 4);
    part += __shfl_xor(part, 8);
    part += __shfl_xor(part, 16);
    part += __shfl_xor(part, 32);
    if (l == 0) out[(size_t)blockIdx.x * 4 + wid] = part * 0.1f;
  }
}

// ---------------------------------------------------------------------------
extern "C" void kernel_launch(void* const* d_in, const int* in_sizes, int n_in,
                              void* d_out, int out_size, void* d_ws, size_t ws_size,
                              hipStream_t stream) {
  const float* queries  = (const float*)d_in[0];
  const float* supports = (const float*)d_in[1];
  const float* W1 = (const float*)d_in[2];
  const float* b1 = (const float*)d_in[3];
  const float* W2 = (const float*)d_in[4];
  const float* b2 = (const float*)d_in[5];
  const float* W3 = (const float*)d_in[6];
  const float* b3 = (const float*)d_in[7];
  const float* W4 = (const float*)d_in[8];
  const float* b4 = (const float*)d_in[9];
  float* out = (float*)d_out;

  // workspace layout (fp32 A/Bm, then bf16 fragment buffers) ~2.35 MB
  float* A  = (float*)d_ws;                       // [2048][256]
  float* Bm = A + (size_t)QN * H1N;               // [160][256]
  ushort* fb2 = (ushort*)(Bm + (size_t)NROW * H1N);  // 64*512
  ushort* fb3 = fb2 + 64 * 512;                      // 16*512
  ushort* fb4 = fb3 + 16 * 512;                      // 2*512

  hipLaunchKernelGGL(k_pre, dim3(PRE_AB_BLOCKS + 21), dim3(256), 0, stream,
                     queries, supports, W1, b1, W2, W3, W4, A, Bm, fb2, fb3, fb4);
  hipLaunchKernelGGL(k_main, dim3((QN * CN * SN) / 64), dim3(256), 0, stream,
                     A, Bm, fb2, fb3, fb4, b2, b3, b4, out);
}

// Round 10
// 72.213 us; speedup vs baseline: 1.8064x; 1.1393x over previous
//
#include <hip/hip_runtime.h>
#include <hip/hip_bf16.h>
#include <math.h>

// Problem constants
#define QN 2048
#define CN 10
#define SN 16
#define DN 256
#define H1N 256
#define H2N 128
#define H3N 64
#define H4N 10
#define NROW 160        // C*S support rows
#define PRE_AB_BLOCKS (QN / 4 + NROW / 4)   // 552

// Padded LDS row strides (bytes): stride/4 ≡ 4 (mod 32) -> each row shifts
// 4 banks, so the 8 lane-octs of a ds_read_b128 hit disjoint bank windows.
#define S1 528   // h1: 256 bf16 = 512B + 16 pad
#define S2 272   // h2: 128 bf16 = 256B + 16 pad
#define S3 144   // h3:  64 bf16 = 128B + 16 pad

typedef __attribute__((ext_vector_type(8)))  short  bf16x8s;  // 8 bf16 = 4 VGPR
typedef __attribute__((ext_vector_type(4)))  float  f32x4;
typedef __attribute__((ext_vector_type(16))) float  f32x16;

static __device__ __forceinline__ unsigned short f2bf(float f) {
  __hip_bfloat16 h = __float2bfloat16(f);
  return __builtin_bit_cast(unsigned short, h);
}

static __device__ __forceinline__ float fast_tanh(float x) {
  const float xc = fminf(fmaxf(x, -15.f), 15.f);
  const float e = __expf(2.f * xc);
  return (e - 1.f) / (e + 1.f);
}

// ---------------------------------------------------------------------------
// Kernel 1 (merged): layer-1 factorization + weight fragment packing.
// ---------------------------------------------------------------------------
__global__ __launch_bounds__(256) void k_pre(
    const float* __restrict__ queries, const float* __restrict__ supports,
    const float* __restrict__ W1, const float* __restrict__ b1,
    const float* __restrict__ W2, const float* __restrict__ W3,
    const float* __restrict__ W4,
    float* __restrict__ A, float* __restrict__ Bm,
    ushort* __restrict__ fb2, ushort* __restrict__ fb3, ushort* __restrict__ fb4) {
  __shared__ float xs[4][DN];
  const int bid = blockIdx.x;
  const int t = threadIdx.x;

  if (bid < PRE_AB_BLOCKS) {
    const bool isA = bid < (QN / 4);
    const int row0 = isA ? bid * 4 : (bid - QN / 4) * 4;
    const float* src = isA ? (queries + (size_t)row0 * DN) : (supports + (size_t)row0 * DN);
    for (int r = 0; r < 4; ++r) xs[r][t] = src[r * DN + t];
    __syncthreads();
    const float* w = W1 + (isA ? 0 : DN * H1N) + t;  // column t
    float acc0 = 0.f, acc1 = 0.f, acc2 = 0.f, acc3 = 0.f;
#pragma unroll 8
    for (int d = 0; d < DN; ++d) {
      const float wv = w[(size_t)d * H1N];
      acc0 += xs[0][d] * wv;
      acc1 += xs[1][d] * wv;
      acc2 += xs[2][d] * wv;
      acc3 += xs[3][d] * wv;
    }
    const float bias = isA ? b1[t] : 0.f;
    float* dst = isA ? A : Bm;
    dst[(row0 + 0) * H1N + t] = acc0 + bias;
    dst[(row0 + 1) * H1N + t] = acc1 + bias;
    dst[(row0 + 2) * H1N + t] = acc2 + bias;
    dst[(row0 + 3) * H1N + t] = acc3 + bias;
    return;
  }

  // ---- weight packing ----
  const int f = (bid - PRE_AB_BLOCKS) * 4 + (t >> 6);
  const int l = t & 63;
  if (f >= 82) return;
  ushort o[8];
  if (f < 64) {
    const int ct = f >> 4, ks = f & 15;
    const int col = ct * 32 + (l & 31);
    const int k0 = ks * 16 + (l >> 5) * 8;
#pragma unroll
    for (int j = 0; j < 8; ++j) o[j] = f2bf(W2[(size_t)(k0 + j) * H2N + col]);
#pragma unroll
    for (int j = 0; j < 8; ++j) fb2[(size_t)f * 512 + l * 8 + j] = o[j];
  } else if (f < 80) {
    const int g = f - 64;
    const int ct = g >> 3, ks = g & 7;
    const int col = ct * 32 + (l & 31);
    const int k0 = ks * 16 + (l >> 5) * 8;
#pragma unroll
    for (int j = 0; j < 8; ++j) o[j] = f2bf(W3[(size_t)(k0 + j) * H3N + col]);
#pragma unroll
    for (int j = 0; j < 8; ++j) fb3[(size_t)g * 512 + l * 8 + j] = o[j];
  } else {
    const int ks = f - 80;
    const int col = l & 15;
    const int k0 = ks * 32 + (l >> 4) * 8;
#pragma unroll
    for (int j = 0; j < 8; ++j)
      o[j] = (col < H4N) ? f2bf(W4[(size_t)(k0 + j) * H4N + col]) : (ushort)0;
#pragma unroll
    for (int j = 0; j < 8; ++j) fb4[(size_t)ks * 512 + l * 8 + j] = o[j];
  }
}

// ---------------------------------------------------------------------------
// Kernel 2: MFMA layers 2-4 + tanh + mean + item-sum.
// Block = 128 rows, 8 waves: wr = wid>>1 (row quarter), wc = wid&1 (col half).
// Padded-stride LDS (no XOR swizzle); h2s/h3s alias the h1s region.
// 67.6 KB LDS -> 2 blocks/CU = 16 waves/CU guaranteed.
// ---------------------------------------------------------------------------
__global__ __launch_bounds__(512, 2) void k_main(
    const float* __restrict__ A, const float* __restrict__ Bm,
    const ushort* __restrict__ fb2, const ushort* __restrict__ fb3,
    const ushort* __restrict__ fb4,
    const float* __restrict__ b2, const float* __restrict__ b3,
    const float* __restrict__ b4, float* __restrict__ out) {
  __shared__ __align__(16) unsigned char smem[128 * S1];   // 67584 B
  unsigned char* h1s = smem;              // [128][256 bf16] stride S1
  unsigned char* h2s = smem;              // [128][128 bf16] stride S2 (alias)
  unsigned char* h3s = smem + 128 * S2;   // [128][ 64 bf16] stride S3 (disjoint)

  const int t = threadIdx.x;
  const int wid = t >> 6;        // 0..7
  const int l = t & 63;
  const int l31 = l & 31;
  const int l15 = l & 15;
  const int wr = wid >> 1;       // 0..3 (32-row group)
  const int wc = wid & 1;        // 0..1 (col half)

  // ---- stage h1 = relu(A[q] + Bm[b]) -> LDS bf16 (padded rows)
  const int rg0 = blockIdx.x * 128;
  const int q0 = rg0 / NROW;
  const int b0 = rg0 - q0 * NROW;
#pragma unroll 4
  for (int r = 0; r < 16; ++r) {
    const int row = wid * 16 + r;           // wave-uniform
    int bb = b0 + row;
    int qq = q0;
    if (bb >= NROW) { bb -= NROW; qq += 1; }
    const float4 av = *(const float4*)(A + (size_t)qq * DN + l * 4);
    const float4 bv = *(const float4*)(Bm + (size_t)bb * DN + l * 4);
    ushort4 o;
    o.x = f2bf(fmaxf(av.x + bv.x, 0.f));
    o.y = f2bf(fmaxf(av.y + bv.y, 0.f));
    o.z = f2bf(fmaxf(av.z + bv.z, 0.f));
    o.w = f2bf(fmaxf(av.w + bv.w, 0.f));
    *(ushort4*)(h1s + row * S1 + l * 8) = o;
  }
  __syncthreads();

  // ---- GEMM2: h2 = relu(h1 @ W2 + b2); wave: 32 rows x 64 cols
  const bf16x8s* fb2v = (const bf16x8s*)fb2;
  f32x16 acc2a, acc2b;
#pragma unroll
  for (int i = 0; i < 16; ++i) { acc2a[i] = 0.f; acc2b[i] = 0.f; }
  {
    const unsigned char* abase = h1s + (32 * wr + l31) * S1;
    const int kh = (l >> 5) * 16;
    const int ct0 = wc * 2;
#pragma unroll
    for (int ks = 0; ks < 16; ++ks) {
      const bf16x8s a = *(const bf16x8s*)(abase + ks * 32 + kh);
      const bf16x8s bA = fb2v[((ct0 + 0) * 16 + ks) * 64 + l];
      const bf16x8s bB = fb2v[((ct0 + 1) * 16 + ks) * 64 + l];
      acc2a = __builtin_amdgcn_mfma_f32_32x32x16_bf16(a, bA, acc2a, 0, 0, 0);
      acc2b = __builtin_amdgcn_mfma_f32_32x32x16_bf16(a, bB, acc2b, 0, 0, 0);
    }
  }
  __syncthreads();   // all h1s reads complete before h2s (alias) writes
  {
    const int c0 = 64 * wc + l31;
    const float bias0 = b2[c0], bias1 = b2[c0 + 32];
#pragma unroll
    for (int reg = 0; reg < 16; ++reg) {
      const int row = 32 * wr + (reg & 3) + 8 * (reg >> 2) + 4 * (l >> 5);
      *(ushort*)(h2s + row * S2 + c0 * 2) =
          f2bf(fmaxf(acc2a[reg] + bias0, 0.f));
      *(ushort*)(h2s + row * S2 + c0 * 2 + 64) =
          f2bf(fmaxf(acc2b[reg] + bias1, 0.f));
    }
  }
  __syncthreads();

  // ---- GEMM3: h3 = relu(h2 @ W3 + b3); wave: 32 rows x 32 cols
  const bf16x8s* fb3v = (const bf16x8s*)fb3;
  f32x16 acc3;
#pragma unroll
  for (int i = 0; i < 16; ++i) acc3[i] = 0.f;
  {
    const unsigned char* abase = h2s + (32 * wr + l31) * S2;
    const int kh = (l >> 5) * 16;
#pragma unroll
    for (int ks = 0; ks < 8; ++ks) {
      const bf16x8s a = *(const bf16x8s*)(abase + ks * 32 + kh);
      const bf16x8s bb = fb3v[(wc * 8 + ks) * 64 + l];
      acc3 = __builtin_amdgcn_mfma_f32_32x32x16_bf16(a, bb, acc3, 0, 0, 0);
    }
  }
  // h3s region is disjoint from h2s -> no barrier needed before writes
  {
    const int c = 32 * wc + l31;
    const float bias = b3[c];
#pragma unroll
    for (int reg = 0; reg < 16; ++reg) {
      const int row = 32 * wr + (reg & 3) + 8 * (reg >> 2) + 4 * (l >> 5);
      *(ushort*)(h3s + row * S3 + c * 2) =
          f2bf(fmaxf(acc3[reg] + bias, 0.f));
    }
  }
  __syncthreads();

  // ---- GEMM4 (16x16x32): wave wid owns rows 16*wid..+16 (one (q,c) group)
  bf16x8s B4[2];
  const bf16x8s* fb4v = (const bf16x8s*)fb4;
  B4[0] = fb4v[l];
  B4[1] = fb4v[64 + l];
  f32x4 acc4;
#pragma unroll
  for (int i = 0; i < 4; ++i) acc4[i] = 0.f;
  {
    const unsigned char* abase = h3s + (16 * wid + l15) * S3;
#pragma unroll
    for (int ks = 0; ks < 2; ++ks) {
      const bf16x8s a = *(const bf16x8s*)(abase + (l >> 4) * 16 + ks * 64);
      acc4 = __builtin_amdgcn_mfma_f32_16x16x32_bf16(a, B4[ks], acc4, 0, 0, 0);
    }
  }

  // ---- epilogue: tanh, sum 10 cols, mean, sum 16 rows -> score
  {
    const int col = l15;
    const float b4v = (col < H4N) ? b4[col] : 0.f;
    float part = 0.f;
#pragma unroll
    for (int r = 0; r < 4; ++r) {
      const float v = fast_tanh(acc4[r] + b4v);
      part += (col < H4N) ? v : 0.f;
    }
    part += __shfl_xor(part, 1);
    part += __shfl_xor(part, 2);
    part += __shfl_xor(part, 4);
    part += __shfl_xor(part, 8);
    part += __shfl_xor(part, 16);
    part += __shfl_xor(part, 32);
    if (l == 0) out[(size_t)blockIdx.x * 8 + wid] = part * 0.1f;
  }
}

// ---------------------------------------------------------------------------
extern "C" void kernel_launch(void* const* d_in, const int* in_sizes, int n_in,
                              void* d_out, int out_size, void* d_ws, size_t ws_size,
                              hipStream_t stream) {
  const float* queries  = (const float*)d_in[0];
  const float* supports = (const float*)d_in[1];
  const float* W1 = (const float*)d_in[2];
  const float* b1 = (const float*)d_in[3];
  const float* W2 = (const float*)d_in[4];
  const float* b2 = (const float*)d_in[5];
  const float* W3 = (const float*)d_in[6];
  const float* b3 = (const float*)d_in[7];
  const float* W4 = (const float*)d_in[8];
  const float* b4 = (const float*)d_in[9];
  float* out = (float*)d_out;

  // workspace layout (fp32 A/Bm, then bf16 fragment buffers) ~2.35 MB
  float* A  = (float*)d_ws;                       // [2048][256]
  float* Bm = A + (size_t)QN * H1N;               // [160][256]
  ushort* fb2 = (ushort*)(Bm + (size_t)NROW * H1N);  // 64*512
  ushort* fb3 = fb2 + 64 * 512;                      // 16*512
  ushort* fb4 = fb3 + 16 * 512;                      // 2*512

  hipLaunchKernelGGL(k_pre, dim3(PRE_AB_BLOCKS + 21), dim3(256), 0, stream,
                     queries, supports, W1, b1, W2, W3, W4, A, Bm, fb2, fb3, fb4);
  hipLaunchKernelGGL(k_main, dim3((QN * CN * SN) / 128), dim3(512), 0, stream,
                     A, Bm, fb2, fb3, fb4, b2, b3, b4, out);
}